// Round 3
// baseline (123.625 us; speedup 1.0000x reference)
//
#include <hip/hip_runtime.h>
#include <hip/hip_bf16.h>

// EasyExprGNN: B=8, S=4096, N=32, H=32, D=64, O=32. T = B*S = 32768 tokens.
//
// Folded formulation (exact algebra):
//   per (token, n): var = quadratic(nb, ei) via 6 scalars; inv = rsqrt(var+eps)
//   r_j = relu((nb*Ag_j + ei*Cg_j + Dg_j)*inv + nlb_j);  nsum_j = sum_n r_j
//   self: e_j = relu((ex*Asg_j + Dsg_j)*inv_s + slb_j)
//   y_m = [e | nsum] @ G + cvec     (G = branchW2 (x) hW1 fused, 64x64)
//   out = relu(LN64(y)*hlg+hlb) @ hW2 + hb2; masked -> 0
//
// v2 (resubmitted unchanged after infra failure): all weights staged to LDS
// once per block; phase B/C weights read as wave-uniform float4 LDS
// broadcasts (v1 issued ~1500 per-lane uniform global loads per thread ->
// VMEM issue/latency bound).

#define LN_EPS 1e-5f

// ws float layout (written by gnn_fold):
//   [0,32) Ag  [32,64) Cg  [64,96) Dg  [96,128) nlb
//   [128,134) qaa,qcc,qdd,qac,qad,qcd  (+2 pad)
//   [136,168) Asg [168,200) Dsg [200,232) slb  [232,235) saa,sad,sdd
//   [256,4352) G[64][64] (k-major; k<32 self via sW2, k>=32 nsum via nW2)
//   [4352,4416) cvec[64]
__global__ __launch_bounds__(256) void gnn_fold(
    const float* __restrict__ nW1, const float* __restrict__ nb1,
    const float* __restrict__ nlg, const float* __restrict__ nlb,
    const float* __restrict__ nW2, const float* __restrict__ nb2,
    const float* __restrict__ sW1, const float* __restrict__ sb1,
    const float* __restrict__ slg, const float* __restrict__ slb,
    const float* __restrict__ sW2, const float* __restrict__ sb2,
    const float* __restrict__ hW1, const float* __restrict__ hb1,
    float* __restrict__ ws)
{
    int tid = blockIdx.x * 256 + threadIdx.x;   // 0..4095 -> one G entry each
    int k = tid >> 6, m = tid & 63;
    float acc = 0.f;
    if (k < 32) {
        #pragma unroll 8
        for (int i = 0; i < 32; ++i) acc = fmaf(sW2[k*32 + i], hW1[i*64 + m], acc);
    } else {
        int kk = k - 32;
        #pragma unroll 8
        for (int i = 0; i < 32; ++i) acc = fmaf(nW2[kk*32 + i], hW1[(32 + i)*64 + m], acc);
    }
    ws[256 + k*64 + m] = acc;

    if (blockIdx.x == 0) {
        int t = threadIdx.x;
        if (t < 64) {
            // cvec[m] = hb1[m] + sb2 @ hW1_top[:,m] + 32 * nb2 @ hW1_bot[:,m]
            float c = hb1[t];
            for (int i = 0; i < 32; ++i) {
                c = fmaf(sb2[i], hW1[i*64 + t], c);
                c = fmaf(32.f * nb2[i], hW1[(32 + i)*64 + t], c);
            }
            ws[4352 + t] = c;
        } else if (t < 96) {
            int j = t - 64;
            float m0 = 0.f, m1 = 0.f, mb = 0.f;
            for (int i = 0; i < 32; ++i) { m0 += nW1[i]; m1 += nW1[32 + i]; mb += nb1[i]; }
            m0 *= (1.f/32.f); m1 *= (1.f/32.f); mb *= (1.f/32.f);
            float a = nW1[j] - m0, c = nW1[32 + j] - m1, d = nb1[j] - mb;
            ws[j]       = a * nlg[j];
            ws[32 + j]  = c * nlg[j];
            ws[64 + j]  = d * nlg[j];
            ws[96 + j]  = nlb[j];
            float ms = 0.f, msb = 0.f;
            for (int i = 0; i < 32; ++i) { ms += sW1[i]; msb += sb1[i]; }
            ms *= (1.f/32.f); msb *= (1.f/32.f);
            float as = sW1[j] - ms, ds = sb1[j] - msb;
            ws[136 + j] = as * slg[j];
            ws[168 + j] = ds * slg[j];
            ws[200 + j] = slb[j];
        } else if (t == 96) {
            float m0 = 0.f, m1 = 0.f, mb = 0.f;
            for (int i = 0; i < 32; ++i) { m0 += nW1[i]; m1 += nW1[32 + i]; mb += nb1[i]; }
            m0 *= (1.f/32.f); m1 *= (1.f/32.f); mb *= (1.f/32.f);
            float qaa=0,qcc=0,qdd=0,qac=0,qad=0,qcd=0;
            for (int j = 0; j < 32; ++j) {
                float a = nW1[j] - m0, c = nW1[32 + j] - m1, d = nb1[j] - mb;
                qaa += a*a; qcc += c*c; qdd += d*d; qac += a*c; qad += a*d; qcd += c*d;
            }
            ws[128]=qaa*(1.f/32.f); ws[129]=qcc*(1.f/32.f); ws[130]=qdd*(1.f/32.f);
            ws[131]=qac*(1.f/32.f); ws[132]=qad*(1.f/32.f); ws[133]=qcd*(1.f/32.f);
            float ms = 0.f, msb = 0.f;
            for (int i = 0; i < 32; ++i) { ms += sW1[i]; msb += sb1[i]; }
            ms *= (1.f/32.f); msb *= (1.f/32.f);
            float saa=0, sad=0, sdd=0;
            for (int j = 0; j < 32; ++j) {
                float as = sW1[j] - ms, ds = sb1[j] - msb;
                saa += as*as; sad += as*ds; sdd += ds*ds;
            }
            ws[232]=saa*(1.f/32.f); ws[233]=sad*(1.f/32.f); ws[234]=sdd*(1.f/32.f);
        }
    }
}

// ---------------- main kernel: 64 tokens per block of 256 threads ----------------
__global__ __launch_bounds__(256) void gnn_main(
    const float* __restrict__ expr, const float* __restrict__ neighbors,
    const float* __restrict__ edge_info, const int* __restrict__ mask,
    const float* __restrict__ hlg, const float* __restrict__ hlb,
    const float* __restrict__ hW2, const float* __restrict__ hb2,
    const float* __restrict__ ws, float* __restrict__ out)
{
    __shared__ float s_feat[64 * 33 * 2];   // (tok*33+n)*2 + {0:nb, 1:ei}
    __shared__ float s_inv[64 * 33];        // tok*33 + n
    __shared__ float s_X[64 * 65];          // tok*65 + k  (phase B input X, reused for Y')
    __shared__ float s_red[64 * 9];         // tok*9 + w*2 + {0,1}  LN partials
    __shared__ float s_expr[64];
    __shared__ float s_prm[256];            // small folded params (ws[0..256))
    __shared__ float s_G[64 * 64];          // fused G, k-major
    __shared__ float s_cv[64];
    __shared__ float s_h2[64 * 32];         // hW2
    __shared__ float s_hb2[32];
    __shared__ float s_hlg[64];
    __shared__ float s_hlb[64];

    const int t  = threadIdx.x;
    const int g0 = blockIdx.x * 64;         // first global token of this block
    const int bb = g0 >> 12;                // batch (S=4096; 64 divides evenly)
    const int s0 = g0 & 4095;
    const float* nbp = neighbors + ((size_t)bb * 32 * 4096 + s0);
    const float* eip = edge_info + (size_t)g0 * 32;

    // ---- stage weights into LDS (coalesced float4) ----
    if (t < 64) ((float4*)s_prm)[t] = ((const float4*)ws)[t];
    #pragma unroll
    for (int i = 0; i < 4; ++i)
        ((float4*)s_G)[i * 256 + t] = ((const float4*)(ws + 256))[i * 256 + t];
    if (t < 16) ((float4*)s_cv)[t] = ((const float4*)(ws + 4352))[t];
    #pragma unroll
    for (int i = 0; i < 2; ++i)
        ((float4*)s_h2)[i * 256 + t] = ((const float4*)hW2)[i * 256 + t];
    if (t < 32) s_hb2[t] = hb2[t];
    if (t < 64) { s_hlg[t] = hlg[t]; s_hlb[t] = hlb[t]; }

    // ---- stage neighbors (transposing) + edge_info ----
    #pragma unroll
    for (int i = 0; i < 8; ++i) {
        int idx = i * 256 + t;
        int n = idx >> 6, col = idx & 63;   // coalesced 256B reads per wave
        s_feat[(col * 33 + n) * 2 + 0] = nbp[n * 4096 + col];
    }
    #pragma unroll
    for (int i = 0; i < 8; ++i) {
        int idx = i * 256 + t;
        int tok = idx >> 5, n = idx & 31;
        s_feat[(tok * 33 + n) * 2 + 1] = eip[idx];
    }
    if (t < 64) s_expr[t] = expr[g0 + t];
    __syncthreads();

    // ---- inv pass: rsqrt of the LN variance quadratic, per (token, n) ----
    {
        float qaa = s_prm[128], qcc = s_prm[129], qdd = s_prm[130];
        float qac = s_prm[131], qad = s_prm[132], qcd = s_prm[133];
        #pragma unroll
        for (int i = 0; i < 8; ++i) {
            int idx = i * 256 + t;
            int tok = idx >> 5, n = idx & 31;
            float2 f = *(const float2*)&s_feat[(tok * 33 + n) * 2];
            float nb = f.x, ei = f.y;
            float v = qdd + nb * (qaa * nb + 2.f * qad) + ei * (qcc * ei + 2.f * qcd)
                    + 2.f * qac * nb * ei;
            s_inv[tok * 33 + n] = rsqrtf(v + LN_EPS);
        }
    }
    __syncthreads();

    // ---- phase A: neighbor accumulation. 4 threads/token, 8 channels each ----
    const int tok = t >> 2;
    const int jb  = (t & 3) * 8;
    float Ag[8], Cg[8], Dg[8], lbv[8];
    *(float4*)&Ag[0]  = *(const float4*)&s_prm[jb];
    *(float4*)&Ag[4]  = *(const float4*)&s_prm[jb + 4];
    *(float4*)&Cg[0]  = *(const float4*)&s_prm[32 + jb];
    *(float4*)&Cg[4]  = *(const float4*)&s_prm[32 + jb + 4];
    *(float4*)&Dg[0]  = *(const float4*)&s_prm[64 + jb];
    *(float4*)&Dg[4]  = *(const float4*)&s_prm[64 + jb + 4];
    *(float4*)&lbv[0] = *(const float4*)&s_prm[96 + jb];
    *(float4*)&lbv[4] = *(const float4*)&s_prm[96 + jb + 4];

    float nsum[8] = {0,0,0,0,0,0,0,0};
    #pragma unroll 4
    for (int n = 0; n < 32; ++n) {
        float2 f  = *(const float2*)&s_feat[(tok * 33 + n) * 2];
        float inv = s_inv[tok * 33 + n];
        #pragma unroll
        for (int i = 0; i < 8; ++i) {
            float r = fmaf(f.x, Ag[i], Dg[i]);
            r = fmaf(f.y, Cg[i], r);
            r = fmaf(r, inv, lbv[i]);
            nsum[i] += fmaxf(r, 0.f);
        }
    }

    // ---- self branch + write X = [e | nsum] ----
    {
        float As[8], Ds[8], Lb[8];
        *(float4*)&As[0] = *(const float4*)&s_prm[136 + jb];
        *(float4*)&As[4] = *(const float4*)&s_prm[136 + jb + 4];
        *(float4*)&Ds[0] = *(const float4*)&s_prm[168 + jb];
        *(float4*)&Ds[4] = *(const float4*)&s_prm[168 + jb + 4];
        *(float4*)&Lb[0] = *(const float4*)&s_prm[200 + jb];
        *(float4*)&Lb[4] = *(const float4*)&s_prm[200 + jb + 4];
        float ex  = s_expr[tok];
        float saa = s_prm[232], sad = s_prm[233], sdd = s_prm[234];
        float vs  = fmaf(ex, fmaf(ex, saa, 2.f * sad), sdd);
        float invs = rsqrtf(vs + LN_EPS);
        #pragma unroll
        for (int i = 0; i < 8; ++i) {
            float r = fmaf(ex, As[i], Ds[i]);
            r = fmaf(r, invs, Lb[i]);
            s_X[tok * 65 + jb + i]      = fmaxf(r, 0.f);
            s_X[tok * 65 + 32 + jb + i] = nsum[i];
        }
    }
    __syncthreads();

    // ---- phase B: y = X @ G + cvec. wave w owns channels [16w,16w+16), lane = token ----
    const int w = __builtin_amdgcn_readfirstlane(t >> 6);  // wave-uniform
    const int l = t & 63;
    float y[16];
    *(float4*)&y[0]  = *(const float4*)&s_cv[w * 16];
    *(float4*)&y[4]  = *(const float4*)&s_cv[w * 16 + 4];
    *(float4*)&y[8]  = *(const float4*)&s_cv[w * 16 + 8];
    *(float4*)&y[12] = *(const float4*)&s_cv[w * 16 + 12];
    #pragma unroll 4
    for (int k = 0; k < 64; ++k) {
        float xk = s_X[l * 65 + k];                    // stride-65: 2-way = free
        const float* gk = &s_G[k * 64 + w * 16];       // wave-uniform -> broadcast
        float4 g0 = *(const float4*)&gk[0];
        float4 g1 = *(const float4*)&gk[4];
        float4 g2 = *(const float4*)&gk[8];
        float4 g3 = *(const float4*)&gk[12];
        y[0]  = fmaf(xk, g0.x, y[0]);  y[1]  = fmaf(xk, g0.y, y[1]);
        y[2]  = fmaf(xk, g0.z, y[2]);  y[3]  = fmaf(xk, g0.w, y[3]);
        y[4]  = fmaf(xk, g1.x, y[4]);  y[5]  = fmaf(xk, g1.y, y[5]);
        y[6]  = fmaf(xk, g1.z, y[6]);  y[7]  = fmaf(xk, g1.w, y[7]);
        y[8]  = fmaf(xk, g2.x, y[8]);  y[9]  = fmaf(xk, g2.y, y[9]);
        y[10] = fmaf(xk, g2.z, y[10]); y[11] = fmaf(xk, g2.w, y[11]);
        y[12] = fmaf(xk, g3.x, y[12]); y[13] = fmaf(xk, g3.y, y[13]);
        y[14] = fmaf(xk, g3.z, y[14]); y[15] = fmaf(xk, g3.w, y[15]);
    }

    // ---- LN over 64 channels (split across 4 waves) ----
    float sm = 0.f, s2 = 0.f;
    #pragma unroll
    for (int i = 0; i < 16; ++i) { sm += y[i]; s2 = fmaf(y[i], y[i], s2); }
    s_red[l * 9 + w * 2 + 0] = sm;
    s_red[l * 9 + w * 2 + 1] = s2;
    __syncthreads();          // also closes phase-B reads of s_X
    float tot = 0.f, tot2 = 0.f;
    #pragma unroll
    for (int r = 0; r < 4; ++r) {
        tot  += s_red[l * 9 + r * 2 + 0];
        tot2 += s_red[l * 9 + r * 2 + 1];
    }
    float mean = tot * (1.f / 64.f);
    float var  = tot2 * (1.f / 64.f) - mean * mean;
    float linv = rsqrtf(var + LN_EPS);
    #pragma unroll
    for (int i = 0; i < 16; ++i) {
        float v = (y[i] - mean) * linv;
        v = fmaf(v, s_hlg[w * 16 + i], s_hlb[w * 16 + i]);
        y[i] = fmaxf(v, 0.f);
    }
    #pragma unroll
    for (int i = 0; i < 16; ++i) s_X[l * 65 + w * 16 + i] = y[i];  // reuse s_X for Y'
    __syncthreads();

    // ---- phase C: out = Y' @ hW2 + hb2. wave w owns out channels [8w, 8w+8) ----
    const int ob = w * 8;
    float o[8];
    *(float4*)&o[0] = *(const float4*)&s_hb2[ob];
    *(float4*)&o[4] = *(const float4*)&s_hb2[ob + 4];
    #pragma unroll 4
    for (int m = 0; m < 64; ++m) {
        float ym = s_X[l * 65 + m];
        const float* h2 = &s_h2[m * 32 + ob];          // wave-uniform -> broadcast
        float4 h0 = *(const float4*)&h2[0];
        float4 h1 = *(const float4*)&h2[4];
        o[0] = fmaf(ym, h0.x, o[0]); o[1] = fmaf(ym, h0.y, o[1]);
        o[2] = fmaf(ym, h0.z, o[2]); o[3] = fmaf(ym, h0.w, o[3]);
        o[4] = fmaf(ym, h1.x, o[4]); o[5] = fmaf(ym, h1.y, o[5]);
        o[6] = fmaf(ym, h1.z, o[6]); o[7] = fmaf(ym, h1.w, o[7]);
    }
    int mk = mask[g0 + l];
    float4 o0 = make_float4(o[0], o[1], o[2], o[3]);
    float4 o1 = make_float4(o[4], o[5], o[6], o[7]);
    if (mk) { o0 = make_float4(0.f,0.f,0.f,0.f); o1 = o0; }
    float4* op = (float4*)(out + (size_t)(g0 + l) * 32 + ob);
    op[0] = o0;
    op[1] = o1;
}

extern "C" void kernel_launch(void* const* d_in, const int* in_sizes, int n_in,
                              void* d_out, int out_size, void* d_ws, size_t ws_size,
                              hipStream_t stream) {
    const float* expr      = (const float*)d_in[0];
    const float* neighbors = (const float*)d_in[1];
    const float* edge_info = (const float*)d_in[2];
    const int*   mask      = (const int*)d_in[3];
    const float* nW1 = (const float*)d_in[4];
    const float* nb1 = (const float*)d_in[5];
    const float* nlg = (const float*)d_in[6];
    const float* nlb = (const float*)d_in[7];
    const float* nW2 = (const float*)d_in[8];
    const float* nb2 = (const float*)d_in[9];
    const float* sW1 = (const float*)d_in[10];
    const float* sb1 = (const float*)d_in[11];
    const float* slg = (const float*)d_in[12];
    const float* slb = (const float*)d_in[13];
    const float* sW2 = (const float*)d_in[14];
    const float* sb2 = (const float*)d_in[15];
    const float* hW1 = (const float*)d_in[16];
    const float* hb1 = (const float*)d_in[17];
    const float* hlg = (const float*)d_in[18];
    const float* hlb = (const float*)d_in[19];
    const float* hW2 = (const float*)d_in[20];
    const float* hb2 = (const float*)d_in[21];
    float* ws  = (float*)d_ws;
    float* out = (float*)d_out;

    gnn_fold<<<16, 256, 0, stream>>>(nW1, nb1, nlg, nlb, nW2, nb2,
                                     sW1, sb1, slg, slb, sW2, sb2,
                                     hW1, hb1, ws);
    gnn_main<<<512, 256, 0, stream>>>(expr, neighbors, edge_info, mask,
                                      hlg, hlb, hW2, hb2, ws, out);
}

// Round 4
// 122.338 us; speedup vs baseline: 1.0105x; 1.0105x over previous
//
#include <hip/hip_runtime.h>

// EasyExprGNN: B=8, S=4096, N=32, H=32, D=64, O=32. T = 32768 tokens.
// v3: ONE kernel. Per-block in-LDS weight fold (G = branchW2 (x) hW1, small
// LN-fold params via wave shuffles), inv fused into phase A, phase B blocked
// 2 tokens x 8 ch per thread. No workspace use at all.

#define LN_EPS 1e-5f

__global__ __launch_bounds__(256) void gnn_fused(
    const float* __restrict__ expr, const float* __restrict__ neighbors,
    const float* __restrict__ edge_info, const int* __restrict__ mask,
    const float* __restrict__ nW1, const float* __restrict__ nb1,
    const float* __restrict__ nlg, const float* __restrict__ nlb,
    const float* __restrict__ nW2, const float* __restrict__ nb2,
    const float* __restrict__ sW1, const float* __restrict__ sb1,
    const float* __restrict__ slg, const float* __restrict__ slb,
    const float* __restrict__ sW2, const float* __restrict__ sb2,
    const float* __restrict__ hW1, const float* __restrict__ hb1,
    const float* __restrict__ hlg, const float* __restrict__ hlb,
    const float* __restrict__ hW2, const float* __restrict__ hb2,
    float* __restrict__ out)
{
    __shared__ float s_feat[64 * 33 * 2];   // (tok*33+n)*2 + {0:nb,1:ei}
    __shared__ float s_X[64 * 65];          // tok*65+k ; X=[e|nsum], later Y'
    __shared__ float s_G[64 * 64];          // fused 64x64, k-major
    __shared__ float s_h2[64 * 32];         // hW2
    __shared__ float s_tmp[2 * 32 * 36];    // sW2T/nW2T (i*36+k); later LN partials (tok*20+g*2)
    __shared__ float s_prm[512];            // [0,235) folded small params; [256)hlg [320)hlb [384)hb2 [416)cvec
    __shared__ float s_expr[64];
    // total ~69.6 KB -> 2 blocks/CU

    const int t  = threadIdx.x;
    const int g0 = blockIdx.x * 64;
    const int bb = g0 >> 12;                // batch; 64 | 4096 so no crossing
    const int s0 = g0 & 4095;
    const float* nbp = neighbors + ((size_t)bb * 32 * 4096 + s0);
    const float* eip = edge_info + (size_t)g0 * 32;

    // ================= staging =================
    #pragma unroll
    for (int i = 0; i < 8; ++i) {           // neighbors, transposing; coalesced
        int idx = i * 256 + t;
        int n = idx >> 6, col = idx & 63;
        s_feat[(col * 33 + n) * 2 + 0] = nbp[n * 4096 + col];
    }
    #pragma unroll
    for (int i = 0; i < 8; ++i) {           // edge_info
        int idx = i * 256 + t;
        int tok = idx >> 5, n = idx & 31;
        s_feat[(tok * 33 + n) * 2 + 1] = eip[idx];
    }
    if (t < 64) s_expr[t] = expr[g0 + t];
    #pragma unroll
    for (int i = 0; i < 2; ++i)             // hW2 -> LDS
        ((float4*)s_h2)[i * 256 + t] = ((const float4*)hW2)[i * 256 + t];
    if (t < 64) { s_prm[256 + t] = hlg[t]; s_prm[320 + t] = hlb[t]; }
    if (t < 32) s_prm[384 + t] = hb2[t];
    #pragma unroll
    for (int rep = 0; rep < 4; ++rep) {     // sW2^T, nW2^T into s_tmp (row pad 36)
        int idx = rep * 256 + t;
        int i2 = idx & 31, k2 = idx >> 5;
        s_tmp[i2 * 36 + k2]        = sW2[idx];
        s_tmp[1152 + i2 * 36 + k2] = nW2[idx];
    }

    // ---- small-param fold: lanes 0..31 of wave 0, butterfly sums ----
    if (t < 32) {
        const int j = t;
        float w0 = nW1[j], w1 = nW1[32 + j], b1v = nb1[j];
        float sw = sW1[j], sb = sb1[j];
        float m0 = w0, m1 = w1, mb = b1v, ms = sw, msb = sb;
        #pragma unroll
        for (int off = 1; off < 32; off <<= 1) {
            m0  += __shfl_xor(m0, off);
            m1  += __shfl_xor(m1, off);
            mb  += __shfl_xor(mb, off);
            ms  += __shfl_xor(ms, off);
            msb += __shfl_xor(msb, off);
        }
        m0 *= (1.f/32.f); m1 *= (1.f/32.f); mb *= (1.f/32.f);
        ms *= (1.f/32.f); msb *= (1.f/32.f);
        float a = w0 - m0, c = w1 - m1, d = b1v - mb;
        float gj = nlg[j];
        s_prm[j]      = a * gj;
        s_prm[32 + j] = c * gj;
        s_prm[64 + j] = d * gj;
        s_prm[96 + j] = nlb[j];
        float as = sw - ms, ds = sb - msb;
        float sgj = slg[j];
        s_prm[136 + j] = as * sgj;
        s_prm[168 + j] = ds * sgj;
        s_prm[200 + j] = slb[j];
        float qaa=a*a, qcc=c*c, qdd=d*d, qac=a*c, qad=a*d, qcd=c*d;
        float saa=as*as, sad=as*ds, sdd=ds*ds;
        #pragma unroll
        for (int off = 1; off < 32; off <<= 1) {
            qaa += __shfl_xor(qaa, off); qcc += __shfl_xor(qcc, off);
            qdd += __shfl_xor(qdd, off); qac += __shfl_xor(qac, off);
            qad += __shfl_xor(qad, off); qcd += __shfl_xor(qcd, off);
            saa += __shfl_xor(saa, off); sad += __shfl_xor(sad, off);
            sdd += __shfl_xor(sdd, off);
        }
        if (j == 0) {
            s_prm[128]=qaa*(1.f/32.f); s_prm[129]=qcc*(1.f/32.f); s_prm[130]=qdd*(1.f/32.f);
            s_prm[131]=qac*(1.f/32.f); s_prm[132]=qad*(1.f/32.f); s_prm[133]=qcd*(1.f/32.f);
            s_prm[232]=saa*(1.f/32.f); s_prm[233]=sad*(1.f/32.f); s_prm[234]=sdd*(1.f/32.f);
        }
    }
    __syncthreads();   // ---- barrier A: staging + small fold done ----

    // ================= G fold: wave w computes k-strip [16w,16w+16), lane m ====
    {
        const int w = t >> 6;
        const int m = t & 63;
        const float* hcol = hW1 + m + ((w < 2) ? 0 : 32 * 64);
        const float* wbase = (w < 2) ? (s_tmp + w * 16) : (s_tmp + 1152 + (w - 2) * 16);
        float g[16];
        #pragma unroll
        for (int kk = 0; kk < 16; ++kk) g[kk] = 0.f;
        #pragma unroll 4
        for (int i = 0; i < 32; ++i) {
            float hv = hcol[i * 64];
            const float* wr = wbase + i * 36;           // 16B-aligned (144B rows)
            float4 wa = *(const float4*)&wr[0];
            float4 wb = *(const float4*)&wr[4];
            float4 wc = *(const float4*)&wr[8];
            float4 wd = *(const float4*)&wr[12];
            g[0]=fmaf(wa.x,hv,g[0]);  g[1]=fmaf(wa.y,hv,g[1]);
            g[2]=fmaf(wa.z,hv,g[2]);  g[3]=fmaf(wa.w,hv,g[3]);
            g[4]=fmaf(wb.x,hv,g[4]);  g[5]=fmaf(wb.y,hv,g[5]);
            g[6]=fmaf(wb.z,hv,g[6]);  g[7]=fmaf(wb.w,hv,g[7]);
            g[8]=fmaf(wc.x,hv,g[8]);  g[9]=fmaf(wc.y,hv,g[9]);
            g[10]=fmaf(wc.z,hv,g[10]); g[11]=fmaf(wc.w,hv,g[11]);
            g[12]=fmaf(wd.x,hv,g[12]); g[13]=fmaf(wd.y,hv,g[13]);
            g[14]=fmaf(wd.z,hv,g[14]); g[15]=fmaf(wd.w,hv,g[15]);
        }
        const int k0 = w * 16;
        #pragma unroll
        for (int kk = 0; kk < 16; ++kk) s_G[(k0 + kk) * 64 + m] = g[kk];
    }
    if (t >= 192) {    // cvec on wave 3
        const int m = t - 192;
        float c = hb1[m];
        #pragma unroll 4
        for (int i = 0; i < 32; ++i) {
            c = fmaf(sb2[i], hW1[i * 64 + m], c);
            c = fmaf(32.f * nb2[i], hW1[(32 + i) * 64 + m], c);
        }
        s_prm[416 + m] = c;
    }

    // ================= phase A: neighbor loop, 4 thr/token, inv fused ========
    {
        const int tok = t >> 2;
        const int jb  = (t & 3) * 8;
        float Ag[8], Cg[8], Dg[8], lbv[8];
        *(float4*)&Ag[0]  = *(const float4*)&s_prm[jb];
        *(float4*)&Ag[4]  = *(const float4*)&s_prm[jb + 4];
        *(float4*)&Cg[0]  = *(const float4*)&s_prm[32 + jb];
        *(float4*)&Cg[4]  = *(const float4*)&s_prm[32 + jb + 4];
        *(float4*)&Dg[0]  = *(const float4*)&s_prm[64 + jb];
        *(float4*)&Dg[4]  = *(const float4*)&s_prm[64 + jb + 4];
        *(float4*)&lbv[0] = *(const float4*)&s_prm[96 + jb];
        *(float4*)&lbv[4] = *(const float4*)&s_prm[96 + jb + 4];
        const float qaa = s_prm[128], qcc = s_prm[129], qdd = s_prm[130];
        const float qac = s_prm[131], qad = s_prm[132], qcd = s_prm[133];

        float nsum[8] = {0,0,0,0,0,0,0,0};
        #pragma unroll 4
        for (int n = 0; n < 32; ++n) {
            float2 f = *(const float2*)&s_feat[(tok * 33 + n) * 2];
            float v = qdd + f.x * fmaf(qaa, f.x, 2.f * qad)
                    + f.y * fmaf(qcc, f.y, 2.f * qcd)
                    + 2.f * qac * f.x * f.y;
            float inv = rsqrtf(v + LN_EPS);
            #pragma unroll
            for (int i = 0; i < 8; ++i) {
                float r = fmaf(f.x, Ag[i], Dg[i]);
                r = fmaf(f.y, Cg[i], r);
                r = fmaf(r, inv, lbv[i]);
                nsum[i] += fmaxf(r, 0.f);
            }
        }
        // self branch + write X
        float As[8], Ds[8], Lb[8];
        *(float4*)&As[0] = *(const float4*)&s_prm[136 + jb];
        *(float4*)&As[4] = *(const float4*)&s_prm[136 + jb + 4];
        *(float4*)&Ds[0] = *(const float4*)&s_prm[168 + jb];
        *(float4*)&Ds[4] = *(const float4*)&s_prm[168 + jb + 4];
        *(float4*)&Lb[0] = *(const float4*)&s_prm[200 + jb];
        *(float4*)&Lb[4] = *(const float4*)&s_prm[200 + jb + 4];
        float ex = s_expr[tok];
        float vs = fmaf(ex, fmaf(ex, s_prm[232], 2.f * s_prm[233]), s_prm[234]);
        float invs = rsqrtf(vs + LN_EPS);
        #pragma unroll
        for (int i = 0; i < 8; ++i) {
            float r = fmaf(ex, As[i], Ds[i]);
            r = fmaf(r, invs, Lb[i]);
            s_X[tok * 65 + jb + i]      = fmaxf(r, 0.f);
            s_X[tok * 65 + 32 + jb + i] = nsum[i];
        }
    }
    __syncthreads();   // ---- barrier B: s_X and s_G complete ----

    // ================= phase B: y = X@G + cvec, 2 tok x 8 ch per thread ======
    const int w4 = __builtin_amdgcn_readfirstlane(t >> 6);
    const int l  = t & 63;
    const int gi = w4 * 2 + (l >> 5);       // channel group 0..7 -> ch [8gi,8gi+8)
    const int tl = (l & 31) * 2;            // token pair tl, tl+1
    float y0[8], y1[8];
    {
        float4 c0 = *(const float4*)&s_prm[416 + 8 * gi];
        float4 c1 = *(const float4*)&s_prm[416 + 8 * gi + 4];
        y0[0]=c0.x; y0[1]=c0.y; y0[2]=c0.z; y0[3]=c0.w;
        y0[4]=c1.x; y0[5]=c1.y; y0[6]=c1.z; y0[7]=c1.w;
        #pragma unroll
        for (int i = 0; i < 8; ++i) y1[i] = y0[i];
    }
    #pragma unroll 4
    for (int k = 0; k < 64; ++k) {
        float xa = s_X[tl * 65 + k];
        float xb = s_X[(tl + 1) * 65 + k];
        const float* gk = &s_G[k * 64 + 8 * gi];
        float4 ga = *(const float4*)&gk[0];
        float4 gb = *(const float4*)&gk[4];
        y0[0]=fmaf(xa,ga.x,y0[0]); y0[1]=fmaf(xa,ga.y,y0[1]);
        y0[2]=fmaf(xa,ga.z,y0[2]); y0[3]=fmaf(xa,ga.w,y0[3]);
        y0[4]=fmaf(xa,gb.x,y0[4]); y0[5]=fmaf(xa,gb.y,y0[5]);
        y0[6]=fmaf(xa,gb.z,y0[6]); y0[7]=fmaf(xa,gb.w,y0[7]);
        y1[0]=fmaf(xb,ga.x,y1[0]); y1[1]=fmaf(xb,ga.y,y1[1]);
        y1[2]=fmaf(xb,ga.z,y1[2]); y1[3]=fmaf(xb,ga.w,y1[3]);
        y1[4]=fmaf(xb,gb.x,y1[4]); y1[5]=fmaf(xb,gb.y,y1[5]);
        y1[6]=fmaf(xb,gb.z,y1[6]); y1[7]=fmaf(xb,gb.w,y1[7]);
    }
    // LN partials (s_tmp reused: tok*20 + gi*2 + {sum, sumsq})
    {
        float sm0=0, ss0=0, sm1=0, ss1=0;
        #pragma unroll
        for (int i = 0; i < 8; ++i) {
            sm0 += y0[i]; ss0 = fmaf(y0[i], y0[i], ss0);
            sm1 += y1[i]; ss1 = fmaf(y1[i], y1[i], ss1);
        }
        s_tmp[tl * 20 + gi * 2 + 0]       = sm0;
        s_tmp[tl * 20 + gi * 2 + 1]       = ss0;
        s_tmp[(tl + 1) * 20 + gi * 2 + 0] = sm1;
        s_tmp[(tl + 1) * 20 + gi * 2 + 1] = ss1;
    }
    __syncthreads();   // ---- barrier C: partials done, phase-B X reads done ----
    {
        // finish LN for both tokens (read 8 pairs each, 16B-aligned rows)
        float4 p0 = *(const float4*)&s_tmp[tl * 20 + 0];
        float4 p1 = *(const float4*)&s_tmp[tl * 20 + 4];
        float4 p2 = *(const float4*)&s_tmp[tl * 20 + 8];
        float4 p3 = *(const float4*)&s_tmp[tl * 20 + 12];
        float tot0  = p0.x + p0.z + p1.x + p1.z + p2.x + p2.z + p3.x + p3.z;
        float tsq0  = p0.y + p0.w + p1.y + p1.w + p2.y + p2.w + p3.y + p3.w;
        float4 q0 = *(const float4*)&s_tmp[(tl + 1) * 20 + 0];
        float4 q1 = *(const float4*)&s_tmp[(tl + 1) * 20 + 4];
        float4 q2 = *(const float4*)&s_tmp[(tl + 1) * 20 + 8];
        float4 q3 = *(const float4*)&s_tmp[(tl + 1) * 20 + 12];
        float tot1  = q0.x + q0.z + q1.x + q1.z + q2.x + q2.z + q3.x + q3.z;
        float tsq1  = q0.y + q0.w + q1.y + q1.w + q2.y + q2.w + q3.y + q3.w;
        float mean0 = tot0 * (1.f/64.f);
        float var0  = tsq0 * (1.f/64.f) - mean0 * mean0;
        float li0   = rsqrtf(var0 + LN_EPS);
        float mean1 = tot1 * (1.f/64.f);
        float var1  = tsq1 * (1.f/64.f) - mean1 * mean1;
        float li1   = rsqrtf(var1 + LN_EPS);
        float4 lg0 = *(const float4*)&s_prm[256 + 8 * gi];
        float4 lg1 = *(const float4*)&s_prm[256 + 8 * gi + 4];
        float4 lb0 = *(const float4*)&s_prm[320 + 8 * gi];
        float4 lb1 = *(const float4*)&s_prm[320 + 8 * gi + 4];
        float lg[8] = {lg0.x,lg0.y,lg0.z,lg0.w,lg1.x,lg1.y,lg1.z,lg1.w};
        float lb[8] = {lb0.x,lb0.y,lb0.z,lb0.w,lb1.x,lb1.y,lb1.z,lb1.w};
        #pragma unroll
        for (int i = 0; i < 8; ++i) {
            float v0 = fmaf((y0[i] - mean0) * li0, lg[i], lb[i]);
            float v1 = fmaf((y1[i] - mean1) * li1, lg[i], lb[i]);
            s_X[tl * 65 + 8 * gi + i]       = fmaxf(v0, 0.f);
            s_X[(tl + 1) * 65 + 8 * gi + i] = fmaxf(v1, 0.f);
        }
    }
    __syncthreads();   // ---- barrier D: Y' complete ----

    // ================= phase C: out = Y'@hW2 + hb2; wave w4 owns ch [8w4,8w4+8)
    {
        const int ob = w4 * 8;
        float o[8];
        *(float4*)&o[0] = *(const float4*)&s_prm[384 + ob];
        *(float4*)&o[4] = *(const float4*)&s_prm[384 + ob + 4];
        #pragma unroll 4
        for (int m = 0; m < 64; ++m) {
            float ym = s_X[l * 65 + m];
            const float* h2 = &s_h2[m * 32 + ob];
            float4 h0 = *(const float4*)&h2[0];
            float4 h1 = *(const float4*)&h2[4];
            o[0]=fmaf(ym,h0.x,o[0]); o[1]=fmaf(ym,h0.y,o[1]);
            o[2]=fmaf(ym,h0.z,o[2]); o[3]=fmaf(ym,h0.w,o[3]);
            o[4]=fmaf(ym,h1.x,o[4]); o[5]=fmaf(ym,h1.y,o[5]);
            o[6]=fmaf(ym,h1.z,o[6]); o[7]=fmaf(ym,h1.w,o[7]);
        }
        int mk = mask[g0 + l];
        float4 o0 = make_float4(o[0], o[1], o[2], o[3]);
        float4 o1 = make_float4(o[4], o[5], o[6], o[7]);
        if (mk) { o0 = make_float4(0.f,0.f,0.f,0.f); o1 = o0; }
        float4* op = (float4*)(out + (size_t)(g0 + l) * 32 + ob);
        op[0] = o0;
        op[1] = o1;
    }
}

extern "C" void kernel_launch(void* const* d_in, const int* in_sizes, int n_in,
                              void* d_out, int out_size, void* d_ws, size_t ws_size,
                              hipStream_t stream) {
    (void)in_sizes; (void)n_in; (void)out_size; (void)d_ws; (void)ws_size;
    const float* expr      = (const float*)d_in[0];
    const float* neighbors = (const float*)d_in[1];
    const float* edge_info = (const float*)d_in[2];
    const int*   mask      = (const int*)d_in[3];
    const float* nW1 = (const float*)d_in[4];
    const float* nb1 = (const float*)d_in[5];
    const float* nlg = (const float*)d_in[6];
    const float* nlb = (const float*)d_in[7];
    const float* nW2 = (const float*)d_in[8];
    const float* nb2 = (const float*)d_in[9];
    const float* sW1 = (const float*)d_in[10];
    const float* sb1 = (const float*)d_in[11];
    const float* slg = (const float*)d_in[12];
    const float* slb = (const float*)d_in[13];
    const float* sW2 = (const float*)d_in[14];
    const float* sb2 = (const float*)d_in[15];
    const float* hW1 = (const float*)d_in[16];
    const float* hb1 = (const float*)d_in[17];
    const float* hlg = (const float*)d_in[18];
    const float* hlb = (const float*)d_in[19];
    const float* hW2 = (const float*)d_in[20];
    const float* hb2 = (const float*)d_in[21];
    float* outp = (float*)d_out;

    gnn_fused<<<512, 256, 0, stream>>>(expr, neighbors, edge_info, mask,
                                       nW1, nb1, nlg, nlb, nW2, nb2,
                                       sW1, sb1, slg, slb, sW2, sb2,
                                       hW1, hb1, hlg, hlb, hW2, hb2, outp);
}